// Round 6
// baseline (52.729 us; speedup 1.0000x reference)
//
#include <hip/hip_runtime.h>

// CARAFE naive upsample: N=2, C=256, H=100, W=100, K=5, G=1, S=2.
// out[n,c,2h+a,2w+b] = sum_{dy,dx} mask[n,dy*5+dx,2h+a,2w+b] * feat[n,c,h+dy-2,w+dx-2]
//
// R1: full 25-tap unroll -> 256 VGPR, latency-bound. 80.7 us.
// R2: (256,4) cap -> scratch spills (1.6 GB traffic). 708 us.
// R3: unroll-1 dy loop, VGPR 72. 50.1 us.
// R4: clamp+mask-zero. 47.2 us. Bound by L1 traffic (channel-strided feats).
// R5: LDS channels-last tiles. 45.2 us. BUT 2.78M bank-conflict cycles
//     (row stride 1024B = bank-aligned; ~5 extra cyc/ds_read) + mask float2
//     at 16B stride = 50% L1 line efficiency (~13 us of L1 BW).
// R6: thread owns TWO adjacent low-res pixels:
//     - masks/stores become lane-dense float4 (100% lines, half the instrs)
//     - 6 window positions serve both pixels' 5 taps (1.67x fewer ds_reads)
//     - LDS swizzle: phys_x = x + (x>>1) (stride-3 f4 per lane pair -> 2-way
//       max = free), plane width 35. For x = 2*wl'+j (j literal) the swizzle
//       folds to 3*wl' + const: zero runtime cost.

#define N_ 2
#define C_ 256
#define H_ 100
#define W_ 100
#define CC 8
#define HW_ (H_ * W_)
#define OW_ (W_ * 2)
#define OHW_ (HW_ * 4)
#define NCHUNK (C_ / CC)          // 32
#define TW 20                     // tile x extent (low-res), even
#define TH 25                     // tile y extent
#define HX 24                     // TW+4 halo cols
#define HY 29                     // TH+4 halo rows
#define PW 35                     // phys plane width (float4): phys(23)=34
#define TILES_X (W_ / TW)         // 5
#define TILES_Y (H_ / TH)         // 4
#define NPAIR (TW / 2)            // 10 pixel-pairs per row

__global__ __launch_bounds__(256) void carafe_kernel(
    const float* __restrict__ feat,
    const float* __restrict__ mask,
    float* __restrict__ out) {

    // float4-granular LDS: plane (y*2+cq), phys x = x + (x>>1), innermost c&3
    __shared__ float lds[HY * 2 * PW * 4];      // 32,480 B

    const int tile = blockIdx.x;
    const int tx = tile % TILES_X;
    const int ty = tile / TILES_X;
    const int cchunk = blockIdx.y;
    const int n = blockIdx.z;
    const int x0 = tx * TW;
    const int y0 = ty * TH;
    const int t = threadIdx.x;

    // ---- stage features: group g (= channel) loads rows 0..28 of the halo ----
    const int lane = t & 31;
    const int g = t >> 5;                        // channel 0..7
    const float* fbase = feat + (n * C_ + cchunk * CC) * HW_;
    {
        const int plane = (g >> 2);              // c/4
        const int elem = (g & 3);                // c%4
        const int physx = lane + (lane >> 1);    // swizzled x
        const int xx = x0 - 2 + lane;
        const bool xok = (lane < HX) & ((unsigned)xx < (unsigned)W_);
#pragma unroll
        for (int r = 0; r < HY; ++r) {
            const int yy = y0 - 2 + r;
            float v = 0.f;
            if (xok & ((unsigned)yy < (unsigned)H_))
                v = fbase[g * HW_ + yy * W_ + xx];
            if (lane < HX)
                lds[((r * 2 + plane) * PW + physx) * 4 + elem] = v;
        }
    }
    __syncthreads();

    if (t >= NPAIR * TH) return;                 // 250 compute threads
    const int hl = t / NPAIR;                    // 0..24
    const int wp = t % NPAIR;                    // pixel-pair 0..9

    float4 acc[CC][2];                           // [channel][a-row]; xyzw = ow0..ow0+3
#pragma unroll
    for (int c = 0; c < CC; ++c) {
        acc[c][0] = make_float4(0.f, 0.f, 0.f, 0.f);
        acc[c][1] = make_float4(0.f, 0.f, 0.f, 0.f);
    }

    const float4* lds4 = reinterpret_cast<const float4*>(lds);
    const int oh0 = 2 * (y0 + hl);
    const int ow0 = 2 * (x0 + 2 * wp);           // multiple of 4 -> f4 aligned
    const float* mbase = mask + n * (25 * OHW_) + oh0 * OW_ + ow0;

    // phys(2*wp + j) = 3*wp + j + (j>>1)  (j literal): offsets {0,1,3,4,6,7}
    const int sw = 3 * wp;

#pragma unroll 1
    for (int dy = 0; dy < 5; ++dy) {
        const int rb0 = ((hl + dy) * 2 + 0) * PW + sw;
        const int rb1 = rb0 + PW;

        float4 fa[6], fb[6];                     // c0-3, c4-7 at positions j=0..5
#pragma unroll
        for (int j = 0; j < 6; ++j) {
            const int off = j + (j >> 1);        // 0,1,3,4,6,7
            fa[j] = lds4[rb0 + off];
            fb[j] = lds4[rb1 + off];
        }

        const float* mrow_dy = mbase + (dy * 5) * OHW_;
#pragma unroll
        for (int dx = 0; dx < 5; ++dx) {
            const float4 m0 = *reinterpret_cast<const float4*>(mrow_dy + dx * OHW_);
            const float4 m1 = *reinterpret_cast<const float4*>(mrow_dy + dx * OHW_ + OW_);
#pragma unroll
            for (int c = 0; c < CC; ++c) {
                const float fl = (c < 4) ? fa[dx][c] : fb[dx][c - 4];      // pixel 0
                const float fr = (c < 4) ? fa[dx + 1][c] : fb[dx + 1][c - 4]; // pixel 1
                acc[c][0].x = fmaf(fl, m0.x, acc[c][0].x);
                acc[c][0].y = fmaf(fl, m0.y, acc[c][0].y);
                acc[c][0].z = fmaf(fr, m0.z, acc[c][0].z);
                acc[c][0].w = fmaf(fr, m0.w, acc[c][0].w);
                acc[c][1].x = fmaf(fl, m1.x, acc[c][1].x);
                acc[c][1].y = fmaf(fl, m1.y, acc[c][1].y);
                acc[c][1].z = fmaf(fr, m1.z, acc[c][1].z);
                acc[c][1].w = fmaf(fr, m1.w, acc[c][1].w);
            }
        }
    }

    float* obase = out + (n * C_ + cchunk * CC) * OHW_ + oh0 * OW_ + ow0;
#pragma unroll
    for (int c = 0; c < CC; ++c) {
        *reinterpret_cast<float4*>(obase + c * OHW_) = acc[c][0];
        *reinterpret_cast<float4*>(obase + c * OHW_ + OW_) = acc[c][1];
    }
}

extern "C" void kernel_launch(void* const* d_in, const int* in_sizes, int n_in,
                              void* d_out, int out_size, void* d_ws, size_t ws_size,
                              hipStream_t stream) {
    const float* feat = (const float*)d_in[0];
    const float* mask = (const float*)d_in[1];
    float* out = (float*)d_out;

    dim3 grid(TILES_X * TILES_Y, NCHUNK, N_);    // 20 x 32 x 2 = 1280 blocks
    carafe_kernel<<<grid, 256, 0, stream>>>(feat, mask, out);
}

// Round 8
// 38.081 us; speedup vs baseline: 1.3847x; 1.3847x over previous
//
#include <hip/hip_runtime.h>

// CARAFE naive upsample: N=2, C=256, H=100, W=100, K=5, G=1, S=2.
// out[n,c,2h+a,2w+b] = sum_{dy,dx} mask[n,dy*5+dx,2h+a,2w+b] * feat[n,c,h+dy-2,w+dx-2]
//
// R1: full 25-tap unroll -> 256 VGPR, latency-bound. 80.7 us.
// R2: (256,4) cap -> scratch spills. 708 us.
// R3: unroll-1 dy loop. 50.1 us.
// R4: clamp+mask-zero, L1 features. 47.2 us (L1 thrash from 40KB c-stride).
// R5: LDS channels-last. 45.2 us. 2.78M bank-conflict cycles: row stride 32
//     f4 (=0 mod 8 bank-groups) -> the 3 hl-runs of a wave collide 3-way.
// R6: pixel-pair threads. 52.7 us REGRESSION. Reverted.
// R7: staging ds_write_b128 + odd stride + pk-fma + chunk-major grid, but
//     RSTR=17 < row extent 29 -> rows overlapped -> WRONG OUTPUT.
// R8: RSTR=29 (>= HX, odd). Read runs offset 58 = 2 mod 8 bank-groups ->
//     disjoint phases, ~conflict-free. Writes: consecutive-lane b128.

typedef float v2f __attribute__((ext_vector_type(2)));

#define N_ 2
#define C_ 256
#define H_ 100
#define W_ 100
#define CC 8
#define HW_ (H_ * W_)
#define OW_ (W_ * 2)
#define OHW_ (HW_ * 4)
#define NCHUNK (C_ / CC)          // 32
#define TW 25
#define TH 10
#define HX 29                     // halo cols (TW+4)
#define NROW 28                   // 14 halo rows x 2 channel-quads
#define RSTR 29                   // float4 row stride: >= HX and odd
#define TILES_X (W_ / TW)         // 4
#define TILES_Y (H_ / TH)         // 10
#define TILES (TILES_X * TILES_Y) // 40

__global__ __launch_bounds__(256) void carafe_kernel(
    const float* __restrict__ feat,
    const float* __restrict__ mask,
    float* __restrict__ out) {

    // row p = y*2 + cq (y: halo row 0..13, cq: channel quad); float4 index
    // p*29 + x, innermost c%4.
    __shared__ float4 lds4[NROW * RSTR];   // 28*29*16 = 12,992 B

    const int cchunk = blockIdx.x;         // chunk-major: 32 blocks sharing a
    const int tile   = blockIdx.y;         // tile's mask slice dispatch together
    const int n      = blockIdx.z;
    const int tx = tile % TILES_X;
    const int ty = tile / TILES_X;
    const int x0 = tx * TW;
    const int y0 = ty * TH;
    const int t = threadIdx.x;
    const int lane = t & 31;
    const int g = t >> 5;                  // 8 groups

    // ---- stage: thread gathers 4 channels at (yy, xx), writes one float4 ----
    {
        const float* fb = feat + (n * C_ + cchunk * CC) * HW_;
        const int xx = x0 - 2 + lane;
        const bool xok = (lane < HX) & ((unsigned)xx < (unsigned)W_);
#pragma unroll
        for (int r = 0; r < 4; ++r) {
            const int p = g * 4 + r;       // 0..31, active < 28
            const int y = p >> 1;
            const int cq = p & 1;
            const int yy = y0 - 2 + y;
            float v0 = 0.f, v1 = 0.f, v2 = 0.f, v3 = 0.f;
            if (xok & ((unsigned)yy < (unsigned)H_) & (p < NROW)) {
                const int o = (cq * 4) * HW_ + yy * W_ + xx;
                v0 = fb[o];
                v1 = fb[o + HW_];
                v2 = fb[o + 2 * HW_];
                v3 = fb[o + 3 * HW_];
            }
            if ((p < NROW) & (lane < HX))
                lds4[p * RSTR + lane] = make_float4(v0, v1, v2, v3);
        }
    }
    __syncthreads();

    if (t >= TH * TW) return;              // 250 compute threads
    const int hl = t / TW;
    const int wl = t % TW;

    v2f a0[CC], a1[CC];
#pragma unroll
    for (int c = 0; c < CC; ++c) { a0[c] = (v2f){0.f, 0.f}; a1[c] = (v2f){0.f, 0.f}; }

    const int oh0 = 2 * (y0 + hl);
    const int ow0 = 2 * (x0 + wl);
    const float* mbase = mask + n * (25 * OHW_) + oh0 * OW_ + ow0;

#pragma unroll 2
    for (int dy = 0; dy < 5; ++dy) {
        const int ry = (hl + dy) * 2;
        const float* mrow_dy = mbase + (dy * 5) * OHW_;
#pragma unroll
        for (int dx = 0; dx < 5; ++dx) {
            const v2f m0 = *reinterpret_cast<const v2f*>(mrow_dy + dx * OHW_);        // a=0
            const v2f m1 = *reinterpret_cast<const v2f*>(mrow_dy + dx * OHW_ + OW_);  // a=1
            const float4 lo = lds4[ry * RSTR + wl + dx];        // c0..3
            const float4 hi = lds4[(ry + 1) * RSTR + wl + dx];  // c4..7
            const float f[8] = {lo.x, lo.y, lo.z, lo.w, hi.x, hi.y, hi.z, hi.w};
#pragma unroll
            for (int c = 0; c < CC; ++c) {
                const v2f fv = {f[c], f[c]};
                a0[c] = __builtin_elementwise_fma(fv, m0, a0[c]);   // v_pk_fma_f32
                a1[c] = __builtin_elementwise_fma(fv, m1, a1[c]);
            }
        }
    }

    float* ob = out + (n * C_ + cchunk * CC) * OHW_ + oh0 * OW_ + ow0;
#pragma unroll
    for (int c = 0; c < CC; ++c) {
        *reinterpret_cast<v2f*>(ob + c * OHW_) = a0[c];
        *reinterpret_cast<v2f*>(ob + c * OHW_ + OW_) = a1[c];
    }
}

extern "C" void kernel_launch(void* const* d_in, const int* in_sizes, int n_in,
                              void* d_out, int out_size, void* d_ws, size_t ws_size,
                              hipStream_t stream) {
    const float* feat = (const float*)d_in[0];
    const float* mask = (const float*)d_in[1];
    float* out = (float*)d_out;

    dim3 grid(NCHUNK, TILES, N_);   // 32 x 40 x 2 = 2560 blocks
    carafe_kernel<<<grid, 256, 0, stream>>>(feat, mask, out);
}